// Round 7
// baseline (1132.186 us; speedup 1.0000x reference)
//
#include <hip/hip_runtime.h>
#include <math.h>

// ---------------- problem constants ----------------
#define TARGET_SCALE 0.06f
constexpr int N_ = 8, S_ = 2048, C_ = 4, V_ = 128, K_ = 512;
constexpr int NS = N_ * S_;       // 16384 (n,s) pairs
constexpr int NQ = NS * C_;       // 65536 queries

// output layout (floats, concatenated in reference return order)
constexpr int O_DISC = 0;                  // [N,S,C,V]
constexpr int O_IDX  = NQ * V_;
constexpr int O_VQ   = O_IDX + NQ;
constexpr int O_ENC  = O_VQ + NQ;
constexpr int O_ENT  = O_ENC + NQ;         // scalar

// workspace layout (floats)
constexpr int WS_EMB  = 0;                 // normalized emb, C*K*V
constexpr int WS_E2   = C_ * K_ * V_;      // e2 per code, C*K
constexpr int WS_HIST = WS_E2 + C_ * K_;   // 512 bins

// ---------------- tiling ----------------
constexpr int QB  = 64;    // queries per block (staged once in LDS)
constexpr int KCH = 128;   // codes per k-chunk (4 chunks over K=512)
constexpr int VCH = 32;    // v per chunk (4 chunks over V=128)
constexpr int XSP = 132;   // XS row stride (floats); 132%32=4 -> xv reads conflict-free
// ES: 2 buffers [128 rows][32 floats], UNPADDED + XOR-swizzled:
//   f4-slot s of row r lives at float offset r*32 + ((s ^ (r&7))<<2)
//   -> ev reads: 16 kg rows, (kg&7) spans 0..7 twice -> 2-way bank aliasing = free

// =====================================================================
// Kernel 1: normalize embeddings, e2, zero histogram
// =====================================================================
__global__ __launch_bounds__(256) void prep_emb(const float* __restrict__ emb0,
                                                float* __restrict__ ws) {
    const int wave = threadIdx.x >> 6;
    const int lane = threadIdx.x & 63;
    const int row  = blockIdx.x * 4 + wave;            // 0..2047 = c*512+k
    const float tn = TARGET_SCALE * sqrtf((float)V_);

    float2 e = *(const float2*)(emb0 + row * V_ + lane * 2);
    float ss = e.x * e.x + e.y * e.y;
    #pragma unroll
    for (int off = 32; off; off >>= 1) ss += __shfl_xor(ss, off);
    const float nrm = sqrtf(ss);

    float2 en;
    en.x = (tn * e.x) / nrm;    // mimic reference elementwise mul-then-div
    en.y = (tn * e.y) / nrm;
    *(float2*)(ws + WS_EMB + row * V_ + lane * 2) = en;

    float s2 = en.x * en.x + en.y * en.y;
    #pragma unroll
    for (int off = 32; off; off >>= 1) s2 += __shfl_xor(s2, off);
    if (lane == 0) ws[WS_E2 + row] = s2;

    if (blockIdx.x == 0) {   // zero histogram (ws is poisoned every launch)
        ws[WS_HIST + threadIdx.x]       = 0.f;
        ws[WS_HIST + 256 + threadIdx.x] = 0.f;
    }
}

// =====================================================================
// Kernel 2: distances + argmin + all per-query outputs
// grid (NS/QB=256, C=4): 1024 blocks, 2 resident/CU (LDS ~70KB) = 2 rounds.
// block: 256 thr = 16 qg x 16 kg; thread tile 4q x 8k = 32 accs.
// Per v-quad: 12 ds_read_b128 -> 128 FMAs; X reads 16-lane broadcast.
// x0 read from HBM exactly once (LDS-resident per tile); E streams via L2.
// =====================================================================
__global__ __launch_bounds__(256, 2) void vq_main(const float* __restrict__ x0,
                                                  float* __restrict__ ws,
                                                  float* __restrict__ out) {
    __shared__ float XS[QB * XSP];        // 33792 B raw x0 rows (resident all tile)
    __shared__ float ES[2 * KCH * VCH];   // 32768 B swizzled emb chunk, double-buffered
    __shared__ float s_es2[K_];           // 2048 B
    __shared__ float s_scale[QB];
    __shared__ float s_x2[QB];
    __shared__ int   s_bestk[QB];

    const int c      = blockIdx.y;
    const int tid    = threadIdx.x;
    const int kg     = tid & 15;          // 0..15
    const int qg     = tid >> 4;          // 0..15
    const int nsBase = blockIdx.x * QB;
    const float tn   = TARGET_SCALE * sqrtf((float)V_);

    const float* __restrict__ embc = ws + WS_EMB + c * K_ * V_;
    const float* __restrict__ e2c  = ws + WS_E2 + c * K_;
    float* __restrict__ hist = ws + WS_HIST;

    // ---- stage XS (raw x0, read from HBM once) + e2 ----
    #pragma unroll
    for (int it = 0; it < 8; ++it) {
        int fi  = tid + 256 * it;              // 0..2047 f4 slots
        int row = fi >> 5, u4 = fi & 31;
        float4 v = *(const float4*)(x0 + ((size_t)(nsBase + row) * C_ + c) * V_ + u4 * 4);
        *(float4*)(XS + row * XSP + u4 * 4) = v;
    }
    s_es2[tid]       = e2c[tid];
    s_es2[tid + 256] = e2c[tid + 256];
    __syncthreads();

    // ---- pass 1: per-row scale & x2 from LDS (4 threads per row) ----
    {
        const int row = tid >> 2, j = tid & 3;
        const float* xr = XS + row * XSP + j * 32;
        float ss = 0.f;
        #pragma unroll
        for (int m = 0; m < 8; ++m) {
            float4 v = *(const float4*)(xr + m * 4);
            ss += v.x * v.x + v.y * v.y + v.z * v.z + v.w * v.w;
        }
        ss += __shfl_xor(ss, 1);
        ss += __shfl_xor(ss, 2);
        const float scale = tn / sqrtf(ss);
        float x2 = 0.f;
        #pragma unroll
        for (int m = 0; m < 8; ++m) {
            float4 v = *(const float4*)(xr + m * 4);
            float a = scale * v.x, b = scale * v.y, d = scale * v.z, e = scale * v.w;
            x2 += a * a + b * b + d * d + e * e;
        }
        x2 += __shfl_xor(x2, 1);
        x2 += __shfl_xor(x2, 2);
        if (j == 0) { s_scale[row] = scale; s_x2[row] = x2; }
    }

    // ---- E staging geometry (reg-staged, swizzled ds_write) ----
    const int sr   = tid >> 3;                              // base row 0..31 (+32*i)
    const int ssl  = tid & 7;                               // f4 slot 0..7
    const int woff = sr * VCH + ((ssl ^ (sr & 7)) << 2);    // (sr+32i)&7 == sr&7
    float4 stg[4];

    // prologue: load + write chunk 0 (buf 0)
    #pragma unroll
    for (int i = 0; i < 4; ++i)
        stg[i] = *(const float4*)(embc + (size_t)(sr + 32 * i) * V_ + ssl * 4);
    #pragma unroll
    for (int i = 0; i < 4; ++i)
        *(float4*)(ES + woff + i * 32 * VCH) = stg[i];

    // bk init 0 (not INT_MAX): even in a pathological all-compares-false
    // world the epilogue index stays in-bounds. Numerically a no-op.
    float bd[4]; int bk[4];
    #pragma unroll
    for (int qq = 0; qq < 4; ++qq) { bd[qq] = 3.4e38f; bk[qq] = 0; }

    __syncthreads();   // pass-1 results + chunk 0 visible

    float rscale[4], rx2[4];
    #pragma unroll
    for (int qq = 0; qq < 4; ++qq) {
        rscale[qq] = s_scale[qg + 16 * qq];
        rx2[qq]    = s_x2[qg + 16 * qq];
    }

    float acc[4][8];

    // ---- main loop: 16 chunks (kc 0..3 x vc 0..3), 1 barrier each ----
    for (int t = 0; t < 16; ++t) {
        const int vc = t & 3, kc = t >> 2;
        const float* EB = ES + (t & 1) * (KCH * VCH);

        if (vc == 0) {
            #pragma unroll
            for (int qq = 0; qq < 4; ++qq)
                #pragma unroll
                for (int kk = 0; kk < 8; ++kk) acc[qq][kk] = 0.f;
        }
        if (t < 15) {   // issue next-chunk loads; latency hides under compute
            const int t1 = t + 1, kc1 = t1 >> 2, vc1 = t1 & 3;
            #pragma unroll
            for (int i = 0; i < 4; ++i)
                stg[i] = *(const float4*)(embc + (size_t)(kc1 * KCH + sr + 32 * i) * V_
                                          + vc1 * VCH + ssl * 4);
        }

        #pragma unroll
        for (int vq = 0; vq < 8; ++vq) {
            float4 ev[8], xv[4];
            #pragma unroll
            for (int kk = 0; kk < 8; ++kk)
                ev[kk] = *(const float4*)(EB + (kg + 16 * kk) * VCH + ((vq ^ (kg & 7)) << 2));
            #pragma unroll
            for (int qq = 0; qq < 4; ++qq)
                xv[qq] = *(const float4*)(XS + (qg + 16 * qq) * XSP + vc * VCH + vq * 4);
            #pragma unroll
            for (int qq = 0; qq < 4; ++qq)
                #pragma unroll
                for (int kk = 0; kk < 8; ++kk) {
                    acc[qq][kk] = fmaf(xv[qq].x, ev[kk].x, acc[qq][kk]);
                    acc[qq][kk] = fmaf(xv[qq].y, ev[kk].y, acc[qq][kk]);
                    acc[qq][kk] = fmaf(xv[qq].z, ev[kk].z, acc[qq][kk]);
                    acc[qq][kk] = fmaf(xv[qq].w, ev[kk].w, acc[qq][kk]);
                }
        }

        if (t < 15) {   // write next chunk into the other buffer (no reader this phase)
            float* WB = ES + ((t + 1) & 1) * (KCH * VCH);
            #pragma unroll
            for (int i = 0; i < 4; ++i)
                *(float4*)(WB + woff + i * 32 * VCH) = stg[i];
        }

        if (vc == 3) {  // full dot done for this kc: fold into running argmin
            #pragma unroll
            for (int kk = 0; kk < 8; ++kk) {
                const int kloc  = kg + 16 * kk;
                const float e2v = s_es2[kc * KCH + kloc];
                const int kglob = kc * KCH + kloc;
                #pragma unroll
                for (int qq = 0; qq < 4; ++qq) {
                    const float xe = rscale[qq] * acc[qq][kk];
                    const float d  = fmaf(-2.f, xe, rx2[qq] + e2v);
                    if (d < bd[qq]) { bd[qq] = d; bk[qq] = kglob; }
                }
            }
        }
        __syncthreads();
    }

    // ---- cross-kg argmin reduce (16 consecutive lanes share qg) ----
    #pragma unroll
    for (int off = 8; off; off >>= 1) {
        #pragma unroll
        for (int qq = 0; qq < 4; ++qq) {
            float od = __shfl_xor(bd[qq], off);
            int   ok = __shfl_xor(bk[qq], off);
            if (od < bd[qq] || (od == bd[qq] && ok < bk[qq])) { bd[qq] = od; bk[qq] = ok; }
        }
    }
    if (kg == 0) {
        #pragma unroll
        for (int qq = 0; qq < 4; ++qq) s_bestk[qg + 16 * qq] = bk[qq];
    }
    __syncthreads();

    // ---- epilogue: 4 threads per query; x0 from LDS, code row from L2 ----
    {
        const int q = tid >> 2, j = tid & 3;
        int kstar = s_bestk[q];
        kstar = kstar < 0 ? 0 : (kstar > K_ - 1 ? K_ - 1 : kstar);   // defensive clamp (never binds)
        const float scale = s_scale[q];
        const size_t qglob = (size_t)(nsBase + q) * C_ + c;
        const float* er = embc + (size_t)kstar * V_ + j * 32;
        const float* xr = XS + q * XSP + j * 32;
        float* dr = out + O_DISC + qglob * V_ + j * 32;
        float vqp = 0.f, en2 = 0.f;
        #pragma unroll
        for (int m = 0; m < 8; ++m) {
            float4 e4 = *(const float4*)(er + m * 4);
            float4 x4 = *(const float4*)(xr + m * 4);
            float xa = scale * x4.x, xb = scale * x4.y, xc = scale * x4.z, xd = scale * x4.w;
            float da = xa - e4.x, db = xb - e4.y, dc = xc - e4.z, dd = xd - e4.w;
            vqp += da * da + db * db + dc * dc + dd * dd;
            float ga = xa - x4.x, gb = xb - x4.y, gc = xc - x4.z, gd = xd - x4.w;
            en2 += ga * ga + gb * gb + gc * gc + gd * gd;
            *(float4*)(dr + m * 4) = e4;   // discrete == chosen code row
        }
        vqp += __shfl_xor(vqp, 1);
        vqp += __shfl_xor(vqp, 2);
        en2 += __shfl_xor(en2, 1);
        en2 += __shfl_xor(en2, 2);
        if (j == 0) {
            out[O_IDX + qglob] = (float)(kstar + c * K_);
            out[O_VQ  + qglob] = vqp;
            out[O_ENC + qglob] = vqp + en2;
            atomicAdd(hist + kstar, 1.0f);
        }
    }
}

// =====================================================================
// Kernel 3: entropy over 512-bin histogram
// NOTE: reference divides by N*S (=16384), NOT N*S*C. prob sums to 4.
// =====================================================================
__global__ __launch_bounds__(256) void entropy_k(const float* __restrict__ ws,
                                                 float* __restrict__ out) {
    const float* hist = ws + WS_HIST;
    const int t = threadIdx.x;
    float s = 0.f;
    for (int i = t; i < K_; i += 256) {
        float h = hist[i];
        if (h > 0.f) {
            float p = h / (float)NS;     // 16384, matches reference
            s += p * logf(p);
        }
    }
    #pragma unroll
    for (int off = 32; off; off >>= 1) s += __shfl_xor(s, off);
    __shared__ float wsum[4];
    if ((t & 63) == 0) wsum[t >> 6] = s;
    __syncthreads();
    if (t == 0) out[O_ENT] = -(wsum[0] + wsum[1] + wsum[2] + wsum[3]);
}

// =====================================================================
extern "C" void kernel_launch(void* const* d_in, const int* in_sizes, int n_in,
                              void* d_out, int out_size, void* d_ws, size_t ws_size,
                              hipStream_t stream) {
    const float* x0   = (const float*)d_in[0];
    const float* emb0 = (const float*)d_in[1];
    float* out = (float*)d_out;
    float* ws  = (float*)d_ws;

    prep_emb<<<512, 256, 0, stream>>>(emb0, ws);
    vq_main<<<dim3(NS / QB, C_), 256, 0, stream>>>(x0, ws, out);
    entropy_k<<<1, 256, 0, stream>>>(ws, out);
}

// Round 8
// 296.147 us; speedup vs baseline: 3.8230x; 3.8230x over previous
//
#include <hip/hip_runtime.h>
#include <math.h>

// ---------------- problem constants ----------------
#define TARGET_SCALE 0.06f
constexpr int N_ = 8, S_ = 2048, C_ = 4, V_ = 128, K_ = 512;
constexpr int NS = N_ * S_;       // 16384 (n,s) pairs
constexpr int NQ = NS * C_;       // 65536 queries

// output layout (floats, concatenated in reference return order)
constexpr int O_DISC = 0;                  // [N,S,C,V]
constexpr int O_IDX  = NQ * V_;
constexpr int O_VQ   = O_IDX + NQ;
constexpr int O_ENC  = O_VQ + NQ;
constexpr int O_ENT  = O_ENC + NQ;         // scalar

// workspace layout (floats)
constexpr int WS_EMB  = 0;                 // normalized emb, C*K*V
constexpr int WS_E2   = C_ * K_ * V_;      // e2 per code, C*K
constexpr int WS_HIST = WS_E2 + C_ * K_;   // 512 bins

// ---------------- tiling ----------------
constexpr int QB  = 64;    // queries per block (staged ONCE in LDS)
constexpr int KCH = 128;   // codes per k-chunk (4 chunks over K=512)
constexpr int VCH = 32;    // v per chunk (4 chunks over V=128)
constexpr int XSP = 132;   // XS row stride (floats)
constexpr int LSP = 36;    // ES row stride (floats) — r2's proven layout

// =====================================================================
// Kernel 1: normalize embeddings, e2, zero histogram
// =====================================================================
__global__ __launch_bounds__(256) void prep_emb(const float* __restrict__ emb0,
                                                float* __restrict__ ws) {
    const int wave = threadIdx.x >> 6;
    const int lane = threadIdx.x & 63;
    const int row  = blockIdx.x * 4 + wave;            // 0..2047 = c*512+k
    const float tn = TARGET_SCALE * sqrtf((float)V_);

    float2 e = *(const float2*)(emb0 + row * V_ + lane * 2);
    float ss = e.x * e.x + e.y * e.y;
    #pragma unroll
    for (int off = 32; off; off >>= 1) ss += __shfl_xor(ss, off);
    const float nrm = sqrtf(ss);

    float2 en;
    en.x = (tn * e.x) / nrm;    // mimic reference elementwise mul-then-div
    en.y = (tn * e.y) / nrm;
    *(float2*)(ws + WS_EMB + row * V_ + lane * 2) = en;

    float s2 = en.x * en.x + en.y * en.y;
    #pragma unroll
    for (int off = 32; off; off >>= 1) s2 += __shfl_xor(s2, off);
    if (lane == 0) ws[WS_E2 + row] = s2;

    if (blockIdx.x == 0) {   // zero histogram (ws is poisoned every launch)
        ws[WS_HIST + threadIdx.x]       = 0.f;
        ws[WS_HIST + 256 + threadIdx.x] = 0.f;
    }
}

// =====================================================================
// Kernel 2: distances + argmin + all per-query outputs
// ROUND-8 = round-2's proven-codegen loop (64 VGPR, no spills) with ONE
// change: X staged in LDS once (x0 read from HBM exactly once).
// grid (256,4); block 256 = 8 qg x 32 kg; thread tile 8q x 4k (acc[8][4]).
// Per-chunk direct global->LDS E staging, 2 barriers per chunk.
// NO register prefetch / double buffer (r7's spill-to-scratch lesson).
// =====================================================================
__global__ __launch_bounds__(256, 2) void vq_main(const float* __restrict__ x0,
                                                  float* __restrict__ ws,
                                                  float* __restrict__ out) {
    __shared__ float XS[QB * XSP];     // 33792 B raw x0 rows (resident all tile)
    __shared__ float ES[KCH * LSP];    // 18432 B E chunk (128 x 32v, stride 36)
    __shared__ float s_es2[K_];        //  2048 B
    __shared__ float s_scale[QB];
    __shared__ float s_x2[QB];
    __shared__ int   s_bestk[QB];

    const int c      = blockIdx.y;
    const int tid    = threadIdx.x;
    const int kg     = tid & 31;       // 0..31
    const int qg     = tid >> 5;       // 0..7
    const int nsBase = blockIdx.x * QB;
    const float tn   = TARGET_SCALE * sqrtf((float)V_);

    const float* __restrict__ embc = ws + WS_EMB + c * K_ * V_;
    const float* __restrict__ e2c  = ws + WS_E2 + c * K_;
    float* __restrict__ hist = ws + WS_HIST;

    // ---- stage XS (raw x0, read from HBM once) + e2 ----
    #pragma unroll
    for (int it = 0; it < 8; ++it) {
        int fi  = tid + 256 * it;              // 0..2047 f4 slots
        int row = fi >> 5, u4 = fi & 31;
        float4 v = *(const float4*)(x0 + ((size_t)(nsBase + row) * C_ + c) * V_ + u4 * 4);
        *(float4*)(XS + row * XSP + u4 * 4) = v;
    }
    s_es2[tid]       = e2c[tid];
    s_es2[tid + 256] = e2c[tid + 256];
    __syncthreads();

    // ---- pass 1: per-row scale & x2 from LDS (4 threads per row) ----
    {
        const int row = tid >> 2, j = tid & 3;
        const float* xr = XS + row * XSP + j * 32;
        float ss = 0.f;
        #pragma unroll
        for (int m = 0; m < 8; ++m) {
            float4 v = *(const float4*)(xr + m * 4);
            ss += v.x * v.x + v.y * v.y + v.z * v.z + v.w * v.w;
        }
        ss += __shfl_xor(ss, 1);
        ss += __shfl_xor(ss, 2);
        const float scale = tn / sqrtf(ss);
        float x2 = 0.f;
        #pragma unroll
        for (int m = 0; m < 8; ++m) {
            float4 v = *(const float4*)(xr + m * 4);
            float a = scale * v.x, b = scale * v.y, d = scale * v.z, e = scale * v.w;
            x2 += a * a + b * b + d * d + e * e;
        }
        x2 += __shfl_xor(x2, 1);
        x2 += __shfl_xor(x2, 2);
        if (j == 0) { s_scale[row] = scale; s_x2[row] = x2; }
    }
    // no barrier needed here: the kc-loop opens with __syncthreads()

    // bk init 0 + later clamp: hardening, numerically a no-op
    float bd[8]; int bk[8];
    #pragma unroll
    for (int qq = 0; qq < 8; ++qq) { bd[qq] = 3.4e38f; bk[qq] = 0; }

    // ---- k-chunk loop (4 kc x 4 vc), direct staging, 2 barriers/chunk ----
    for (int kc = 0; kc < K_ / KCH; ++kc) {
        float acc[8][4];
        #pragma unroll
        for (int qq = 0; qq < 8; ++qq)
            #pragma unroll
            for (int kk = 0; kk < 4; ++kk) acc[qq][kk] = 0.f;

        for (int vc = 0; vc < V_ / VCH; ++vc) {
            __syncthreads();   // previous chunk's readers done with ES
            // stage E chunk: 128 rows x 32 v (4 float4 per thread, coalesced)
            #pragma unroll
            for (int it = 0; it < 4; ++it) {
                int fi = tid + 256 * it;            // 0..1023
                int r = fi >> 3, slot = fi & 7;
                float4 v = *(const float4*)(embc + (size_t)(kc * KCH + r) * V_
                                            + vc * VCH + slot * 4);
                *(float4*)(ES + r * LSP + slot * 4) = v;
            }
            __syncthreads();

            // compute: 8 vq steps; 12 LDS f4 reads -> 128 FMAs per thread
            #pragma unroll
            for (int vq = 0; vq < 8; ++vq) {
                float4 ev[4], xv[8];
                #pragma unroll
                for (int kk = 0; kk < 4; ++kk)
                    ev[kk] = *(const float4*)(ES + (kg + 32 * kk) * LSP + vq * 4);
                #pragma unroll
                for (int qq = 0; qq < 8; ++qq)
                    xv[qq] = *(const float4*)(XS + (qg + 8 * qq) * XSP + vc * VCH + vq * 4);
                #pragma unroll
                for (int qq = 0; qq < 8; ++qq)
                    #pragma unroll
                    for (int kk = 0; kk < 4; ++kk) {
                        acc[qq][kk] = fmaf(xv[qq].x, ev[kk].x, acc[qq][kk]);
                        acc[qq][kk] = fmaf(xv[qq].y, ev[kk].y, acc[qq][kk]);
                        acc[qq][kk] = fmaf(xv[qq].z, ev[kk].z, acc[qq][kk]);
                        acc[qq][kk] = fmaf(xv[qq].w, ev[kk].w, acc[qq][kk]);
                    }
            }
        }

        // fold chunk into running argmin: d2 = (x2+e2) - 2*scale*acc
        #pragma unroll
        for (int kk = 0; kk < 4; ++kk) {
            const int kloc  = kg + 32 * kk;
            const float e2v = s_es2[kc * KCH + kloc];
            const int kglob = kc * KCH + kloc;
            #pragma unroll
            for (int qq = 0; qq < 8; ++qq) {
                const int ql = qg + 8 * qq;
                const float xe = s_scale[ql] * acc[qq][kk];
                const float d  = fmaf(-2.f, xe, s_x2[ql] + e2v);
                if (d < bd[qq]) { bd[qq] = d; bk[qq] = kglob; }
            }
        }
    }

    // ---- cross-kg argmin reduce (32 lanes share a qg), tie -> lower k ----
    #pragma unroll
    for (int off = 16; off; off >>= 1) {
        #pragma unroll
        for (int qq = 0; qq < 8; ++qq) {
            float od = __shfl_xor(bd[qq], off);
            int   ok = __shfl_xor(bk[qq], off);
            if (od < bd[qq] || (od == bd[qq] && ok < bk[qq])) { bd[qq] = od; bk[qq] = ok; }
        }
    }
    if (kg == 0) {
        #pragma unroll
        for (int qq = 0; qq < 8; ++qq) s_bestk[qg + 8 * qq] = bk[qq];
    }
    __syncthreads();

    // ---- epilogue: 4 threads per query; x0 from LDS, code row from L2 ----
    {
        const int q = tid >> 2, j = tid & 3;
        int kstar = s_bestk[q];
        kstar = kstar < 0 ? 0 : (kstar > K_ - 1 ? K_ - 1 : kstar);   // never binds
        const float scale = s_scale[q];
        const size_t qglob = (size_t)(nsBase + q) * C_ + c;
        const float* er = embc + (size_t)kstar * V_ + j * 32;
        const float* xr = XS + q * XSP + j * 32;
        float* dr = out + O_DISC + qglob * V_ + j * 32;
        float vqp = 0.f, en2 = 0.f;
        #pragma unroll
        for (int m = 0; m < 8; ++m) {
            float4 e4 = *(const float4*)(er + m * 4);
            float4 x4 = *(const float4*)(xr + m * 4);
            float xa = scale * x4.x, xb = scale * x4.y, xc = scale * x4.z, xd = scale * x4.w;
            float da = xa - e4.x, db = xb - e4.y, dc = xc - e4.z, dd = xd - e4.w;
            vqp += da * da + db * db + dc * dc + dd * dd;
            float ga = xa - x4.x, gb = xb - x4.y, gc = xc - x4.z, gd = xd - x4.w;
            en2 += ga * ga + gb * gb + gc * gc + gd * gd;
            *(float4*)(dr + m * 4) = e4;   // discrete == chosen code row
        }
        vqp += __shfl_xor(vqp, 1);
        vqp += __shfl_xor(vqp, 2);
        en2 += __shfl_xor(en2, 1);
        en2 += __shfl_xor(en2, 2);
        if (j == 0) {
            out[O_IDX + qglob] = (float)(kstar + c * K_);
            out[O_VQ  + qglob] = vqp;
            out[O_ENC + qglob] = vqp + en2;
            atomicAdd(hist + kstar, 1.0f);
        }
    }
}

// =====================================================================
// Kernel 3: entropy over 512-bin histogram
// NOTE: reference divides by N*S (=16384), NOT N*S*C. prob sums to 4.
// =====================================================================
__global__ __launch_bounds__(256) void entropy_k(const float* __restrict__ ws,
                                                 float* __restrict__ out) {
    const float* hist = ws + WS_HIST;
    const int t = threadIdx.x;
    float s = 0.f;
    for (int i = t; i < K_; i += 256) {
        float h = hist[i];
        if (h > 0.f) {
            float p = h / (float)NS;     // 16384, matches reference
            s += p * logf(p);
        }
    }
    #pragma unroll
    for (int off = 32; off; off >>= 1) s += __shfl_xor(s, off);
    __shared__ float wsum[4];
    if ((t & 63) == 0) wsum[t >> 6] = s;
    __syncthreads();
    if (t == 0) out[O_ENT] = -(wsum[0] + wsum[1] + wsum[2] + wsum[3]);
}

// =====================================================================
extern "C" void kernel_launch(void* const* d_in, const int* in_sizes, int n_in,
                              void* d_out, int out_size, void* d_ws, size_t ws_size,
                              hipStream_t stream) {
    const float* x0   = (const float*)d_in[0];
    const float* emb0 = (const float*)d_in[1];
    float* out = (float*)d_out;
    float* ws  = (float*)d_ws;

    prep_emb<<<512, 256, 0, stream>>>(emb0, ws);
    vq_main<<<dim3(NS / QB, C_), 256, 0, stream>>>(x0, ws, out);
    entropy_k<<<1, 256, 0, stream>>>(ws, out);
}